// Round 18
// baseline (117.742 us; speedup 1.0000x reference)
//
#include <hip/hip_runtime.h>
#include <cstdint>
#include <cstddef>

typedef __bf16 bf16x8 __attribute__((ext_vector_type(8)));
typedef float f32x4 __attribute__((ext_vector_type(4)));

#define MFMA16(a, b, c) __builtin_amdgcn_mfma_f32_16x16x32_bf16(a, b, c, 0, 0, 0)

static __device__ __forceinline__ bf16x8 ld_bf16x8(const __bf16* p) {
    return *reinterpret_cast<const bf16x8*>(p);
}

static __device__ __forceinline__ void async_cp16(const __bf16* g, __bf16* l) {
    __builtin_amdgcn_global_load_lds((const __attribute__((address_space(1))) void*)g,
                                     (__attribute__((address_space(3))) void*)l, 16, 0, 0);
}

template <int N>
static __device__ __forceinline__ void wait_vmcnt() {
    asm volatile("s_waitcnt vmcnt(%0)" ::"n"(N) : "memory");
}

static __device__ __forceinline__ void barrier_pinned() {
    __builtin_amdgcn_sched_barrier(0);
    __builtin_amdgcn_s_barrier();
    __builtin_amdgcn_sched_barrier(0);
}

static __device__ __forceinline__ float ex2(float x) {
    return __builtin_amdgcn_exp2f(x);  // native v_exp_f32
}

// ---- DPP 16-lane rotate-reduce (pure VALU, no DS pipe) ----
template <int CTRL>
static __device__ __forceinline__ float dppmv(float x) {
    return __builtin_bit_cast(float, __builtin_amdgcn_update_dpp(
        0, __builtin_bit_cast(int, x), CTRL, 0xF, 0xF, true));
}
static __device__ __forceinline__ float rmax16(float x) {
    x = fmaxf(x, dppmv<0x121>(x));
    x = fmaxf(x, dppmv<0x122>(x));
    x = fmaxf(x, dppmv<0x124>(x));
    x = fmaxf(x, dppmv<0x128>(x));
    return x;
}
static __device__ __forceinline__ float rsum16(float x) {
    x += dppmv<0x121>(x);
    x += dppmv<0x122>(x);
    x += dppmv<0x124>(x);
    x += dppmv<0x128>(x);
    return x;
}

// ---------------- f32 -> bf16 convert (8 elems/thread) ----------------
__global__ void cvt_kernel(const float* __restrict__ src, __bf16* __restrict__ dst, int n8) {
    int i = blockIdx.x * blockDim.x + threadIdx.x;
    if (i >= n8) return;
    const float4* s4 = reinterpret_cast<const float4*>(src) + (size_t)i * 2;
    float4 a = s4[0], b = s4[1];
    bf16x8 o;
    o[0] = (__bf16)a.x; o[1] = (__bf16)a.y; o[2] = (__bf16)a.z; o[3] = (__bf16)a.w;
    o[4] = (__bf16)b.x; o[5] = (__bf16)b.y; o[6] = (__bf16)b.z; o[7] = (__bf16)b.w;
    reinterpret_cast<bf16x8*>(dst)[i] = o;
}

// ---------------- transpose-convert: in [K][N] f32 -> out [N][K] bf16 ----------------
__global__ __launch_bounds__(256) void tcvt_kernel(const float* __restrict__ in,
                                                   __bf16* __restrict__ out, int K, int N) {
    __shared__ __bf16 T[64][72];
    const int k0 = blockIdx.y * 64, n0 = blockIdx.x * 64;
    const int t = threadIdx.x;
    const int col = (t & 15) << 2;
    const int rowb = t >> 4;
    #pragma unroll
    for (int i = 0; i < 4; i++) {
        int row = i * 16 + rowb;
        float4 v = *reinterpret_cast<const float4*>(&in[(size_t)(k0 + row) * N + n0 + col]);
        T[col + 0][row] = (__bf16)v.x;
        T[col + 1][row] = (__bf16)v.y;
        T[col + 2][row] = (__bf16)v.z;
        T[col + 3][row] = (__bf16)v.w;
    }
    __syncthreads();
    const int oc = (t & 7) << 3;
    const int orb = t >> 3;
    #pragma unroll
    for (int i = 0; i < 2; i++) {
        int r = i * 32 + orb;
        bf16x8 v = *reinterpret_cast<bf16x8*>(&T[r][oc]);
        *reinterpret_cast<bf16x8*>(&out[(size_t)(n0 + r) * K + k0 + oc]) = v;
    }
}

// ---------------- 5-buffer depth-4 counted-vmcnt mainloop, chunk-XOR swizzled ----------
// Depth-2 (3 buf) measured 47us on qkv: stage(t+2) gives only ~400cy budget vs
// 500-900cy L2 latency -> stall every step. Depth-4 gives ~3 steps (~600+cy).
// Ledger: at step t's wait, outstanding = tiles t..t+3 = 8 loads; vmcnt(6)
// certifies tile t (tail: 4/2/0). stage(t+4) targets buf[(t-1)%5], whose readers
// finished (lgkmcnt(0)) before the barrier at step t. LDS 80KB -> 2 blocks/CU.
template <int BM, int BN, int WM, int WN>
__device__ __forceinline__ void mainloop2(const __bf16* __restrict__ A,
                                          const __bf16* __restrict__ Bt,
                                          int K, int row0, int col0,
                                          __bf16* lds,
                                          f32x4 (&acc)[BM / WM / 16][BN / WN / 16]) {
    constexpr int MR = BM / WM / 16, NR = BN / WN / 16;
    constexpr int AE = BM * 32;
    constexpr int BUFE = AE + BN * 32;
    constexpr int APW = BM / 16 / 8;
    constexpr int BPW = BN / 16 / 8;
    constexpr int NBUF = 5;
    const int tid = threadIdx.x, l = tid & 63, w = tid >> 6;
    const int wm = w / WN, wn = w % WN;
    const int lr = l >> 2;
    const int lcs = (((l & 3) ^ ((l >> 3) & 3)) << 3);  // pre-swizzled source k-offset
    const int fr = l & 15;
    const int fc = (((l >> 4) ^ ((l >> 1) & 3)) << 3);  // swizzled read k-offset

    const size_t arow = (size_t)(row0 + lr) * K + lcs;
    const size_t brow = (size_t)(col0 + lr) * K + lcs;
    const int nt = K >> 5;

    auto stage = [&](int t, int buf) {
        const int k0 = t << 5;
        const int bb = buf * BUFE;
        #pragma unroll
        for (int j = 0; j < APW; j++) {
            const int mi = w * APW + j;
            async_cp16(A + arow + (size_t)mi * 16 * K + k0, lds + bb + mi * 512 + l * 8);
        }
        #pragma unroll
        for (int j = 0; j < BPW; j++) {
            const int ni = w * BPW + j;
            async_cp16(Bt + brow + (size_t)ni * 16 * K + k0, lds + bb + AE + ni * 512 + l * 8);
        }
    };

    // prologue: 4 tiles in flight
    stage(0, 0);
    if (1 < nt) stage(1, 1);
    if (2 < nt) stage(2, 2);
    if (3 < nt) stage(3, 3);

    const int aoff = (wm * (BM / WM) + fr) * 32 + fc;
    const int boff = AE + (wn * (BN / WN) + fr) * 32 + fc;

    int p = 0, q = 4;
    for (int t = 0; t < nt; ++t) {
        const int rem = nt - 1 - t;
        if (rem >= 3) wait_vmcnt<6>();
        else if (rem == 2) wait_vmcnt<4>();
        else if (rem == 1) wait_vmcnt<2>();
        else wait_vmcnt<0>();
        barrier_pinned();
        if (t + 4 < nt) {
            stage(t + 4, q);
            q = (q == NBUF - 1) ? 0 : q + 1;
        }
        const int cb = p * BUFE;
        bf16x8 af[MR], bfv[NR];
        #pragma unroll
        for (int m = 0; m < MR; m++) af[m] = ld_bf16x8(&lds[cb + aoff + m * 512]);
        #pragma unroll
        for (int n = 0; n < NR; n++) bfv[n] = ld_bf16x8(&lds[cb + boff + n * 512]);
        __builtin_amdgcn_s_setprio(1);
        #pragma unroll
        for (int m = 0; m < MR; m++) {
            #pragma unroll
            for (int n = 0; n < NR; n++) {
                acc[m][n] = MFMA16(af[m], bfv[n], acc[m][n]);
            }
        }
        __builtin_amdgcn_s_setprio(0);
        asm volatile("s_waitcnt lgkmcnt(0)" ::: "memory");
        __builtin_amdgcn_sched_barrier(0);
        p = (p == NBUF - 1) ? 0 : p + 1;
    }
}

// ---------------- QKV GEMM: x(4096x1024) @ w_attn^T(3072x1024) + b_attn ----------------
__global__ __launch_bounds__(512, 2) void gemm_qkv_kernel(const __bf16* __restrict__ xb,
                                                          const __bf16* __restrict__ wabt,
                                                          const float* __restrict__ bias,
                                                          __bf16* __restrict__ qb,
                                                          __bf16* __restrict__ kb,
                                                          __bf16* __restrict__ vt,
                                                          float* __restrict__ present) {
    __shared__ __bf16 lds[5 * (128 * 32 + 128 * 32)];  // 80 KB
    f32x4 acc[2][4] = {};
    const int row0 = blockIdx.y * 128, col0 = blockIdx.x * 128;
    mainloop2<128, 128, 4, 2>(xb, wabt, 1024, row0, col0, lds, acc);

    const int l = threadIdx.x & 63, w = threadIdx.x >> 6;
    const int wm = w >> 1, wn = w & 1;
    const int part = col0 >> 10;  // uniform per block: 0=q 1=k 2=v
    #pragma unroll
    for (int n = 0; n < 4; n++) {
        int col = col0 + wn * 64 + n * 16 + (l & 15);
        int hh = (col >> 6) & 15;
        int dd = col & 63;
        float bv = bias[col];
        #pragma unroll
        for (int m = 0; m < 2; m++) {
            #pragma unroll
            for (int r = 0; r < 4; r++) {
                int row = row0 + wm * 32 + m * 16 + ((l >> 4) << 2) + r;
                int bb = row >> 11, ss = row & 2047;
                float val = acc[m][n][r] + bv;
                size_t qi = (((size_t)(bb * 16 + hh)) * 2048 + ss) * 64 + dd;
                if (part == 0) {
                    qb[qi] = (__bf16)val;
                } else if (part == 1) {
                    kb[qi] = (__bf16)val;
                    present[(((size_t)((bb * 2 + 0) * 16 + hh)) * 2048 + ss) * 64 + dd] = val;
                } else {
                    vt[(((size_t)(bb * 16 + hh)) * 64 + dd) * 2048 + ss] = (__bf16)val;
                    present[(((size_t)((bb * 2 + 1) * 16 + hh)) * 2048 + ss) * 64 + dd] = val;
                }
            }
        }
    }
}

// ---------------- Proj GEMM: a(4096x1024) @ w_proj^T(1024x1024) + b_proj ----------------
__global__ __launch_bounds__(512, 2) void gemm_proj_kernel(const __bf16* __restrict__ ab,
                                                           const __bf16* __restrict__ wpbt,
                                                           const float* __restrict__ bias,
                                                           float* __restrict__ out) {
    __shared__ __bf16 lds[5 * (128 * 32 + 128 * 32)];  // 80 KB
    f32x4 acc[2][4] = {};
    const int row0 = blockIdx.y * 128, col0 = blockIdx.x * 128;
    mainloop2<128, 128, 4, 2>(ab, wpbt, 1024, row0, col0, lds, acc);

    const int lane = threadIdx.x & 63, w = threadIdx.x >> 6;
    const int wm = w >> 1, wn = w & 1;
    #pragma unroll
    for (int n = 0; n < 4; n++) {
        int col = col0 + wn * 64 + n * 16 + (lane & 15);
        float bv = bias[col];
        #pragma unroll
        for (int m = 0; m < 2; m++) {
            #pragma unroll
            for (int r = 0; r < 4; r++) {
                int row = row0 + wm * 32 + m * 16 + ((lane >> 4) << 2) + r;
                out[(size_t)row * 1024 + col] = acc[m][n][r] + bv;
            }
        }
    }
}

// ---------------- sliding-window causal flash attention, LDS-staged two-pass ----
__global__ __launch_bounds__(256, 3) void attn_kernel(const __bf16* __restrict__ qb,
                                                      const __bf16* __restrict__ kb,
                                                      const __bf16* __restrict__ vtb,
                                                      __bf16* __restrict__ ab) {
    __shared__ __bf16 Kls[5 * 4096];     // 40 KB: [tile][row 64][elem 64] swizzled
    __shared__ __bf16 Pls[4][16 * 72];   // 9.2 KB per-wave P tiles
    const int bidx = blockIdx.x;
    const int xcd = bidx & 7, idx = bidx >> 3;
    const int bh = (xcd << 2) | (idx & 3);  // 4 heads per XCD (K/V L2-resident)
    const int qc = idx >> 2;                // 64-row q-chunk, 0..31
    const int lane = threadIdx.x & 63, wid = threadIdx.x >> 6;
    const int q0blk = qc * 64;
    const int q0w = q0blk + wid * 16;

    const __bf16* Qh = qb + (size_t)bh * 2048 * 64;
    const __bf16* Kh = kb + (size_t)bh * 2048 * 64;
    const __bf16* Vt = vtb + (size_t)bh * 64 * 2048;
    __bf16* Pw = &Pls[wid][0];

    const int ld16 = lane & 15, hi3 = (lane >> 4) << 3, hi4 = (lane >> 4) << 2;

    int tmp = q0blk - 255;
    const int kt0 = tmp > 0 ? (tmp & ~63) : 0;
    const int NT = ((q0blk + 63 - kt0) >> 6) + 1;  // <= 5

    // ---- stage all K tiles (block-cooperative, source-preswizzled) ----
    const int sswz = (((lane & 7) ^ (lane >> 3)) << 3);  // src elem offset (swizzled)
    for (int j = wid; j < NT * 8; j += 4) {
        const int tj = j >> 3, c = j & 7;
        const int kt = kt0 + tj * 64;
        const __bf16* src = Kh + (size_t)(kt + c * 8 + (lane >> 3)) * 64 + sswz;
        async_cp16(src, &Kls[j * 512 + lane * 8]);
    }

    bf16x8 qf[2];
    {
        const __bf16* qp = Qh + (size_t)(q0w + ld16) * 64 + hi3;
        qf[0] = ld_bf16x8(qp);
        qf[1] = ld_bf16x8(qp + 32);
    }
    wait_vmcnt<0>();
    __syncthreads();  // all waves' staging landed

    const float cl2 = 0.18033688f;  // (1/sqrt(64)) * log2(e)
    const int rdswz = (lane & 7) << 3;  // read-side XOR key

    auto qks = [&](int t, int kt, f32x4 (&s)[4]) {
        const __bf16* tb = &Kls[t * 4096];
        #pragma unroll
        for (int kc = 0; kc < 4; kc++) {
            const int rbase = (kc * 16 + ld16) * 64;
            bf16x8 k0 = ld_bf16x8(&tb[rbase + ((hi3) ^ rdswz)]);
            bf16x8 k1 = ld_bf16x8(&tb[rbase + ((32 + hi3) ^ rdswz)]);
            f32x4 a = (f32x4){0.f, 0.f, 0.f, 0.f};
            a = MFMA16(qf[0], k0, a);
            a = MFMA16(qf[1], k1, a);
            s[kc] = a;
        }
        const bool clean = (kt >= q0w - 240) && (kt + 63 <= q0w);  // wave-uniform
        if (!clean) {
            #pragma unroll
            for (int r = 0; r < 4; r++) {
                int q = q0w + hi4 + r;
                #pragma unroll
                for (int kc = 0; kc < 4; kc++) {
                    int ki = kt + kc * 16 + ld16;
                    bool ok = (ki <= q) && (ki > q - 256);
                    s[kc][r] = ok ? s[kc][r] : -1e30f;
                }
            }
        }
    };

    // ---- pass 1: exact row max over the wave's window ----
    float mr[4] = {-1e30f, -1e30f, -1e30f, -1e30f};
    for (int t = 0; t < NT; t++) {
        const int kt = kt0 + t * 64;
        if (kt + 63 < q0w - 255 || kt > q0w + 15) continue;
        f32x4 s[4];
        qks(t, kt, s);
        #pragma unroll
        for (int r = 0; r < 4; r++) {
            mr[r] = fmaxf(mr[r], fmaxf(fmaxf(s[0][r], s[1][r]), fmaxf(s[2][r], s[3][r])));
        }
    }
    float m2[4];
    #pragma unroll
    for (int r = 0; r < 4; r++) m2[r] = rmax16(mr[r]) * cl2;

    // ---- pass 2: exp, P roundtrip, PV ----
    f32x4 o[4];
    #pragma unroll
    for (int dt = 0; dt < 4; dt++) o[dt] = (f32x4){0.f, 0.f, 0.f, 0.f};
    float sl[4] = {0.f, 0.f, 0.f, 0.f};

    for (int t = 0; t < NT; t++) {
        const int kt = kt0 + t * 64;
        if (kt + 63 < q0w - 255 || kt > q0w + 15) continue;
        bf16x8 va[4], vb[4];
        #pragma unroll
        for (int dt = 0; dt < 4; dt++) {
            const __bf16* vp = &Vt[(size_t)(dt * 16 + ld16) * 2048 + kt + hi3];
            va[dt] = ld_bf16x8(vp);
            vb[dt] = ld_bf16x8(vp + 32);
        }
        f32x4 s[4];
        qks(t, kt, s);
        #pragma unroll
        for (int r = 0; r < 4; r++) {
            float p0 = ex2(fmaf(s[0][r], cl2, -m2[r]));
            float p1 = ex2(fmaf(s[1][r], cl2, -m2[r]));
            float p2 = ex2(fmaf(s[2][r], cl2, -m2[r]));
            float p3 = ex2(fmaf(s[3][r], cl2, -m2[r]));
            sl[r] += (p0 + p1) + (p2 + p3);
            int qrow = hi4 + r;
            Pw[qrow * 72 + ld16]      = (__bf16)p0;
            Pw[qrow * 72 + 16 + ld16] = (__bf16)p1;
            Pw[qrow * 72 + 32 + ld16] = (__bf16)p2;
            Pw[qrow * 72 + 48 + ld16] = (__bf16)p3;
        }
        asm volatile("s_waitcnt lgkmcnt(0)" ::: "memory");
        bf16x8 pfA = ld_bf16x8(&Pw[ld16 * 72 + hi3]);
        bf16x8 pfB = ld_bf16x8(&Pw[ld16 * 72 + 32 + hi3]);
        __builtin_amdgcn_s_setprio(1);
        #pragma unroll
        for (int dt = 0; dt < 4; dt++) o[dt] = MFMA16(pfA, va[dt], o[dt]);
        #pragma unroll
        for (int dt = 0; dt < 4; dt++) o[dt] = MFMA16(pfB, vb[dt], o[dt]);
        __builtin_amdgcn_s_setprio(0);
    }

    // ---- normalize and store ----
    const int bb = bh >> 4, hh = bh & 15;
    #pragma unroll
    for (int r = 0; r < 4; r++) {
        float inv = 1.f / rsum16(sl[r]);
        int q = q0w + hi4 + r;
        size_t base = ((size_t)bb * 2048 + q) * 1024 + hh * 64;
        #pragma unroll
        for (int dt = 0; dt < 4; dt++) {
            ab[base + dt * 16 + ld16] = (__bf16)(o[dt][r] * inv);
        }
    }
}

// ---------------- launch ----------------
extern "C" void kernel_launch(void* const* d_in, const int* in_sizes, int n_in,
                              void* d_out, int out_size, void* d_ws, size_t ws_size,
                              hipStream_t stream) {
    const float* x = (const float*)d_in[0];
    const float* w_attn = (const float*)d_in[1];
    const float* b_attn = (const float*)d_in[2];
    const float* w_proj = (const float*)d_in[3];
    const float* b_proj = (const float*)d_in[4];

    float* out = (float*)d_out;
    float* present = out + (size_t)2 * 2048 * 1024;

    char* w = (char*)d_ws;
    __bf16* xb   = (__bf16*)(w);
    __bf16* wabt = (__bf16*)(w + 8388608);
    __bf16* wpbt = (__bf16*)(w + 14680064);
    __bf16* qb   = (__bf16*)(w + 16777216);
    __bf16* kb   = (__bf16*)(w + 25165824);
    __bf16* vt   = (__bf16*)(w + 33554432);
    __bf16* ab   = xb;

    cvt_kernel<<<2048, 256, 0, stream>>>(x, xb, 524288);
    tcvt_kernel<<<dim3(48, 16), 256, 0, stream>>>(w_attn, wabt, 1024, 3072);
    tcvt_kernel<<<dim3(16, 16), 256, 0, stream>>>(w_proj, wpbt, 1024, 1024);

    gemm_qkv_kernel<<<dim3(24, 32), 512, 0, stream>>>(xb, wabt, b_attn, qb, kb, vt, present);

    attn_kernel<<<1024, 256, 0, stream>>>(qb, kb, vt, ab);

    gemm_proj_kernel<<<dim3(8, 32), 512, 0, stream>>>(ab, wpbt, b_proj, out);
}

// Round 19
// 101.902 us; speedup vs baseline: 1.1554x; 1.1554x over previous
//
#include <hip/hip_runtime.h>
#include <cstdint>
#include <cstddef>

typedef __bf16 bf16x8 __attribute__((ext_vector_type(8)));
typedef float f32x4 __attribute__((ext_vector_type(4)));

#define MFMA16(a, b, c) __builtin_amdgcn_mfma_f32_16x16x32_bf16(a, b, c, 0, 0, 0)

static __device__ __forceinline__ bf16x8 ld_bf16x8(const __bf16* p) {
    return *reinterpret_cast<const bf16x8*>(p);
}

static __device__ __forceinline__ void async_cp16(const __bf16* g, __bf16* l) {
    __builtin_amdgcn_global_load_lds((const __attribute__((address_space(1))) void*)g,
                                     (__attribute__((address_space(3))) void*)l, 16, 0, 0);
}

template <int N>
static __device__ __forceinline__ void wait_vmcnt() {
    asm volatile("s_waitcnt vmcnt(%0)" ::"n"(N) : "memory");
}

static __device__ __forceinline__ void barrier_pinned() {
    __builtin_amdgcn_sched_barrier(0);
    __builtin_amdgcn_s_barrier();
    __builtin_amdgcn_sched_barrier(0);
}

static __device__ __forceinline__ float ex2(float x) {
    return __builtin_amdgcn_exp2f(x);  // native v_exp_f32
}

// ---- DPP 16-lane rotate-reduce (pure VALU, no DS pipe) ----
template <int CTRL>
static __device__ __forceinline__ float dppmv(float x) {
    return __builtin_bit_cast(float, __builtin_amdgcn_update_dpp(
        0, __builtin_bit_cast(int, x), CTRL, 0xF, 0xF, true));
}
static __device__ __forceinline__ float rmax16(float x) {
    x = fmaxf(x, dppmv<0x121>(x));
    x = fmaxf(x, dppmv<0x122>(x));
    x = fmaxf(x, dppmv<0x124>(x));
    x = fmaxf(x, dppmv<0x128>(x));
    return x;
}
static __device__ __forceinline__ float rsum16(float x) {
    x += dppmv<0x121>(x);
    x += dppmv<0x122>(x);
    x += dppmv<0x124>(x);
    x += dppmv<0x128>(x);
    return x;
}

// ---------------- merged prep: f32->bf16 convert + 2 transpose-converts ----------------
// blocks 0..2047: cvt x (8 elems/thread); 2048..2815: tcvt w_attn; 2816..3071: tcvt w_proj.
static __device__ __forceinline__ void tcvt_body(const float* __restrict__ in,
                                                 __bf16* __restrict__ out, int K, int N,
                                                 int bx, int by, __bf16 (*T)[72]) {
    const int k0 = by * 64, n0 = bx * 64;
    const int t = threadIdx.x;
    const int col = (t & 15) << 2;
    const int rowb = t >> 4;
    #pragma unroll
    for (int i = 0; i < 4; i++) {
        int row = i * 16 + rowb;
        float4 v = *reinterpret_cast<const float4*>(&in[(size_t)(k0 + row) * N + n0 + col]);
        T[col + 0][row] = (__bf16)v.x;
        T[col + 1][row] = (__bf16)v.y;
        T[col + 2][row] = (__bf16)v.z;
        T[col + 3][row] = (__bf16)v.w;
    }
    __syncthreads();
    const int oc = (t & 7) << 3;
    const int orb = t >> 3;
    #pragma unroll
    for (int i = 0; i < 2; i++) {
        int r = i * 32 + orb;
        bf16x8 v = *reinterpret_cast<bf16x8*>(&T[r][oc]);
        *reinterpret_cast<bf16x8*>(&out[(size_t)(n0 + r) * K + k0 + oc]) = v;
    }
}

__global__ __launch_bounds__(256) void prep_kernel(const float* __restrict__ x,
                                                   __bf16* __restrict__ xb,
                                                   const float* __restrict__ wa,
                                                   __bf16* __restrict__ wabt,
                                                   const float* __restrict__ wp,
                                                   __bf16* __restrict__ wpbt) {
    __shared__ __bf16 T[64][72];
    const int bid = blockIdx.x;
    if (bid < 2048) {
        int i = bid * 256 + threadIdx.x;
        const float4* s4 = reinterpret_cast<const float4*>(x) + (size_t)i * 2;
        float4 a = s4[0], b = s4[1];
        bf16x8 o;
        o[0] = (__bf16)a.x; o[1] = (__bf16)a.y; o[2] = (__bf16)a.z; o[3] = (__bf16)a.w;
        o[4] = (__bf16)b.x; o[5] = (__bf16)b.y; o[6] = (__bf16)b.z; o[7] = (__bf16)b.w;
        reinterpret_cast<bf16x8*>(xb)[i] = o;
    } else if (bid < 2816) {
        const int t = bid - 2048;  // 768 tiles: 48 x 16
        tcvt_body(wa, wabt, 1024, 3072, t % 48, t / 48, T);
    } else {
        const int t = bid - 2816;  // 256 tiles: 16 x 16
        tcvt_body(wp, wpbt, 1024, 1024, t % 16, t / 16, T);
    }
}

// ---------------- 3-buffer depth-2 counted-vmcnt mainloop, chunk-XOR swizzled ----------
// (best measured config: qkv 47.6us @ grid 24x32, 512 thr, 48KB LDS, 3 blocks/CU)
template <int BM, int BN, int WM, int WN>
__device__ __forceinline__ void mainloop2(const __bf16* __restrict__ A,
                                          const __bf16* __restrict__ Bt,
                                          int K, int row0, int col0,
                                          __bf16* lds,
                                          f32x4 (&acc)[BM / WM / 16][BN / WN / 16]) {
    constexpr int MR = BM / WM / 16, NR = BN / WN / 16;
    constexpr int AE = BM * 32;
    constexpr int BUFE = AE + BN * 32;
    constexpr int APW = BM / 16 / 8;
    constexpr int BPW = BN / 16 / 8;
    const int tid = threadIdx.x, l = tid & 63, w = tid >> 6;
    const int wm = w / WN, wn = w % WN;
    const int lr = l >> 2;
    const int lcs = (((l & 3) ^ ((l >> 3) & 3)) << 3);  // pre-swizzled source k-offset
    const int fr = l & 15;
    const int fc = (((l >> 4) ^ ((l >> 1) & 3)) << 3);  // swizzled read k-offset

    const size_t arow = (size_t)(row0 + lr) * K + lcs;
    const size_t brow = (size_t)(col0 + lr) * K + lcs;
    const int nt = K >> 5;

    auto stage = [&](int t, int buf) {
        const int k0 = t << 5;
        const int bb = buf * BUFE;
        #pragma unroll
        for (int j = 0; j < APW; j++) {
            const int mi = w * APW + j;
            async_cp16(A + arow + (size_t)mi * 16 * K + k0, lds + bb + mi * 512 + l * 8);
        }
        #pragma unroll
        for (int j = 0; j < BPW; j++) {
            const int ni = w * BPW + j;
            async_cp16(Bt + brow + (size_t)ni * 16 * K + k0, lds + bb + AE + ni * 512 + l * 8);
        }
    };

    stage(0, 0);
    stage(1, 1);

    const int aoff = (wm * (BM / WM) + fr) * 32 + fc;
    const int boff = AE + (wn * (BN / WN) + fr) * 32 + fc;

    int p = 0;
    for (int t = 0; t < nt; ++t) {
        if (t + 1 < nt) {
            wait_vmcnt<APW + BPW>();
        } else {
            wait_vmcnt<0>();
        }
        barrier_pinned();
        if (t + 2 < nt) {
            int p2 = p + 2; if (p2 >= 3) p2 -= 3;
            stage(t + 2, p2);
        }
        const int cb = p * BUFE;
        bf16x8 af[MR], bfv[NR];
        #pragma unroll
        for (int m = 0; m < MR; m++) af[m] = ld_bf16x8(&lds[cb + aoff + m * 512]);
        #pragma unroll
        for (int n = 0; n < NR; n++) bfv[n] = ld_bf16x8(&lds[cb + boff + n * 512]);
        __builtin_amdgcn_s_setprio(1);
        #pragma unroll
        for (int m = 0; m < MR; m++) {
            #pragma unroll
            for (int n = 0; n < NR; n++) {
                acc[m][n] = MFMA16(af[m], bfv[n], acc[m][n]);
            }
        }
        __builtin_amdgcn_s_setprio(0);
        asm volatile("s_waitcnt lgkmcnt(0)" ::: "memory");
        __builtin_amdgcn_sched_barrier(0);
        p = (p == 2) ? 0 : p + 1;
    }
}

// ---------------- QKV GEMM: x(4096x1024) @ w_attn^T(3072x1024) + b_attn ----------------
__global__ __launch_bounds__(512, 2) void gemm_qkv_kernel(const __bf16* __restrict__ xb,
                                                          const __bf16* __restrict__ wabt,
                                                          const float* __restrict__ bias,
                                                          __bf16* __restrict__ qb,
                                                          __bf16* __restrict__ kb,
                                                          __bf16* __restrict__ vt,
                                                          float* __restrict__ present) {
    __shared__ __bf16 lds[3 * (128 * 32 + 128 * 32)];  // 48 KB
    f32x4 acc[2][4] = {};
    const int row0 = blockIdx.y * 128, col0 = blockIdx.x * 128;
    mainloop2<128, 128, 4, 2>(xb, wabt, 1024, row0, col0, lds, acc);

    const int l = threadIdx.x & 63, w = threadIdx.x >> 6;
    const int wm = w >> 1, wn = w & 1;
    const int part = col0 >> 10;  // uniform per block: 0=q 1=k 2=v
    #pragma unroll
    for (int n = 0; n < 4; n++) {
        int col = col0 + wn * 64 + n * 16 + (l & 15);
        int hh = (col >> 6) & 15;
        int dd = col & 63;
        float bv = bias[col];
        #pragma unroll
        for (int m = 0; m < 2; m++) {
            #pragma unroll
            for (int r = 0; r < 4; r++) {
                int row = row0 + wm * 32 + m * 16 + ((l >> 4) << 2) + r;
                int bb = row >> 11, ss = row & 2047;
                float val = acc[m][n][r] + bv;
                size_t qi = (((size_t)(bb * 16 + hh)) * 2048 + ss) * 64 + dd;
                if (part == 0) {
                    qb[qi] = (__bf16)val;
                } else if (part == 1) {
                    kb[qi] = (__bf16)val;
                    present[(((size_t)((bb * 2 + 0) * 16 + hh)) * 2048 + ss) * 64 + dd] = val;
                } else {
                    vt[(((size_t)(bb * 16 + hh)) * 64 + dd) * 2048 + ss] = (__bf16)val;
                    present[(((size_t)((bb * 2 + 1) * 16 + hh)) * 2048 + ss) * 64 + dd] = val;
                }
            }
        }
    }
}

// ---------------- Proj GEMM: a(4096x1024) @ w_proj^T(1024x1024) + b_proj ----------------
__global__ __launch_bounds__(512, 2) void gemm_proj_kernel(const __bf16* __restrict__ ab,
                                                           const __bf16* __restrict__ wpbt,
                                                           const float* __restrict__ bias,
                                                           float* __restrict__ out) {
    __shared__ __bf16 lds[3 * (128 * 32 + 128 * 32)];
    f32x4 acc[2][4] = {};
    const int row0 = blockIdx.y * 128, col0 = blockIdx.x * 128;
    mainloop2<128, 128, 4, 2>(ab, wpbt, 1024, row0, col0, lds, acc);

    const int lane = threadIdx.x & 63, w = threadIdx.x >> 6;
    const int wm = w >> 1, wn = w & 1;
    #pragma unroll
    for (int n = 0; n < 4; n++) {
        int col = col0 + wn * 64 + n * 16 + (lane & 15);
        float bv = bias[col];
        #pragma unroll
        for (int m = 0; m < 2; m++) {
            #pragma unroll
            for (int r = 0; r < 4; r++) {
                int row = row0 + wm * 32 + m * 16 + ((lane >> 4) << 2) + r;
                out[(size_t)row * 1024 + col] = acc[m][n][r] + bv;
            }
        }
    }
}

// ---------------- sliding-window causal flash attention, LDS-staged two-pass ----
__global__ __launch_bounds__(256, 3) void attn_kernel(const __bf16* __restrict__ qb,
                                                      const __bf16* __restrict__ kb,
                                                      const __bf16* __restrict__ vtb,
                                                      __bf16* __restrict__ ab) {
    __shared__ __bf16 Kls[5 * 4096];     // 40 KB: [tile][row 64][elem 64] swizzled
    __shared__ __bf16 Pls[4][16 * 72];   // 9.2 KB per-wave P tiles
    const int bidx = blockIdx.x;
    const int xcd = bidx & 7, idx = bidx >> 3;
    const int bh = (xcd << 2) | (idx & 3);  // 4 heads per XCD (K/V L2-resident)
    const int qc = idx >> 2;                // 64-row q-chunk, 0..31
    const int lane = threadIdx.x & 63, wid = threadIdx.x >> 6;
    const int q0blk = qc * 64;
    const int q0w = q0blk + wid * 16;

    const __bf16* Qh = qb + (size_t)bh * 2048 * 64;
    const __bf16* Kh = kb + (size_t)bh * 2048 * 64;
    const __bf16* Vt = vtb + (size_t)bh * 64 * 2048;
    __bf16* Pw = &Pls[wid][0];

    const int ld16 = lane & 15, hi3 = (lane >> 4) << 3, hi4 = (lane >> 4) << 2;

    int tmp = q0blk - 255;
    const int kt0 = tmp > 0 ? (tmp & ~63) : 0;
    const int NT = ((q0blk + 63 - kt0) >> 6) + 1;  // <= 5

    // ---- stage all K tiles (block-cooperative, source-preswizzled) ----
    const int sswz = (((lane & 7) ^ (lane >> 3)) << 3);  // src elem offset (swizzled)
    for (int j = wid; j < NT * 8; j += 4) {
        const int tj = j >> 3, c = j & 7;
        const int kt = kt0 + tj * 64;
        const __bf16* src = Kh + (size_t)(kt + c * 8 + (lane >> 3)) * 64 + sswz;
        async_cp16(src, &Kls[j * 512 + lane * 8]);
    }

    bf16x8 qf[2];
    {
        const __bf16* qp = Qh + (size_t)(q0w + ld16) * 64 + hi3;
        qf[0] = ld_bf16x8(qp);
        qf[1] = ld_bf16x8(qp + 32);
    }
    wait_vmcnt<0>();
    __syncthreads();  // all waves' staging landed

    const float cl2 = 0.18033688f;  // (1/sqrt(64)) * log2(e)
    const int rdswz = (lane & 7) << 3;  // read-side XOR key

    auto qks = [&](int t, int kt, f32x4 (&s)[4]) {
        const __bf16* tb = &Kls[t * 4096];
        #pragma unroll
        for (int kc = 0; kc < 4; kc++) {
            const int rbase = (kc * 16 + ld16) * 64;
            bf16x8 k0 = ld_bf16x8(&tb[rbase + ((hi3) ^ rdswz)]);
            bf16x8 k1 = ld_bf16x8(&tb[rbase + ((32 + hi3) ^ rdswz)]);
            f32x4 a = (f32x4){0.f, 0.f, 0.f, 0.f};
            a = MFMA16(qf[0], k0, a);
            a = MFMA16(qf[1], k1, a);
            s[kc] = a;
        }
        const bool clean = (kt >= q0w - 240) && (kt + 63 <= q0w);  // wave-uniform
        if (!clean) {
            #pragma unroll
            for (int r = 0; r < 4; r++) {
                int q = q0w + hi4 + r;
                #pragma unroll
                for (int kc = 0; kc < 4; kc++) {
                    int ki = kt + kc * 16 + ld16;
                    bool ok = (ki <= q) && (ki > q - 256);
                    s[kc][r] = ok ? s[kc][r] : -1e30f;
                }
            }
        }
    };

    // ---- pass 1: exact row max over the wave's window ----
    float mr[4] = {-1e30f, -1e30f, -1e30f, -1e30f};
    for (int t = 0; t < NT; t++) {
        const int kt = kt0 + t * 64;
        if (kt + 63 < q0w - 255 || kt > q0w + 15) continue;
        f32x4 s[4];
        qks(t, kt, s);
        #pragma unroll
        for (int r = 0; r < 4; r++) {
            mr[r] = fmaxf(mr[r], fmaxf(fmaxf(s[0][r], s[1][r]), fmaxf(s[2][r], s[3][r])));
        }
    }
    float m2[4];
    #pragma unroll
    for (int r = 0; r < 4; r++) m2[r] = rmax16(mr[r]) * cl2;

    // ---- pass 2: exp, P roundtrip, PV ----
    f32x4 o[4];
    #pragma unroll
    for (int dt = 0; dt < 4; dt++) o[dt] = (f32x4){0.f, 0.f, 0.f, 0.f};
    float sl[4] = {0.f, 0.f, 0.f, 0.f};

    for (int t = 0; t < NT; t++) {
        const int kt = kt0 + t * 64;
        if (kt + 63 < q0w - 255 || kt > q0w + 15) continue;
        bf16x8 va[4], vb[4];
        #pragma unroll
        for (int dt = 0; dt < 4; dt++) {
            const __bf16* vp = &Vt[(size_t)(dt * 16 + ld16) * 2048 + kt + hi3];
            va[dt] = ld_bf16x8(vp);
            vb[dt] = ld_bf16x8(vp + 32);
        }
        f32x4 s[4];
        qks(t, kt, s);
        #pragma unroll
        for (int r = 0; r < 4; r++) {
            float p0 = ex2(fmaf(s[0][r], cl2, -m2[r]));
            float p1 = ex2(fmaf(s[1][r], cl2, -m2[r]));
            float p2 = ex2(fmaf(s[2][r], cl2, -m2[r]));
            float p3 = ex2(fmaf(s[3][r], cl2, -m2[r]));
            sl[r] += (p0 + p1) + (p2 + p3);
            int qrow = hi4 + r;
            Pw[qrow * 72 + ld16]      = (__bf16)p0;
            Pw[qrow * 72 + 16 + ld16] = (__bf16)p1;
            Pw[qrow * 72 + 32 + ld16] = (__bf16)p2;
            Pw[qrow * 72 + 48 + ld16] = (__bf16)p3;
        }
        asm volatile("s_waitcnt lgkmcnt(0)" ::: "memory");
        bf16x8 pfA = ld_bf16x8(&Pw[ld16 * 72 + hi3]);
        bf16x8 pfB = ld_bf16x8(&Pw[ld16 * 72 + 32 + hi3]);
        __builtin_amdgcn_s_setprio(1);
        #pragma unroll
        for (int dt = 0; dt < 4; dt++) o[dt] = MFMA16(pfA, va[dt], o[dt]);
        #pragma unroll
        for (int dt = 0; dt < 4; dt++) o[dt] = MFMA16(pfB, vb[dt], o[dt]);
        __builtin_amdgcn_s_setprio(0);
    }

    // ---- normalize and store ----
    const int bb = bh >> 4, hh = bh & 15;
    #pragma unroll
    for (int r = 0; r < 4; r++) {
        float inv = 1.f / rsum16(sl[r]);
        int q = q0w + hi4 + r;
        size_t base = ((size_t)bb * 2048 + q) * 1024 + hh * 64;
        #pragma unroll
        for (int dt = 0; dt < 4; dt++) {
            ab[base + dt * 16 + ld16] = (__bf16)(o[dt][r] * inv);
        }
    }
}

// ---------------- launch ----------------
extern "C" void kernel_launch(void* const* d_in, const int* in_sizes, int n_in,
                              void* d_out, int out_size, void* d_ws, size_t ws_size,
                              hipStream_t stream) {
    const float* x = (const float*)d_in[0];
    const float* w_attn = (const float*)d_in[1];
    const float* b_attn = (const float*)d_in[2];
    const float* w_proj = (const float*)d_in[3];
    const float* b_proj = (const float*)d_in[4];

    float* out = (float*)d_out;
    float* present = out + (size_t)2 * 2048 * 1024;

    char* w = (char*)d_ws;
    __bf16* xb   = (__bf16*)(w);
    __bf16* wabt = (__bf16*)(w + 8388608);
    __bf16* wpbt = (__bf16*)(w + 14680064);
    __bf16* qb   = (__bf16*)(w + 16777216);
    __bf16* kb   = (__bf16*)(w + 25165824);
    __bf16* vt   = (__bf16*)(w + 33554432);
    __bf16* ab   = xb;

    prep_kernel<<<3072, 256, 0, stream>>>(x, xb, w_attn, wabt, w_proj, wpbt);

    gemm_qkv_kernel<<<dim3(24, 32), 512, 0, stream>>>(xb, wabt, b_attn, qb, kb, vt, present);

    attn_kernel<<<1024, 256, 0, stream>>>(qb, kb, vt, ab);

    gemm_proj_kernel<<<dim3(8, 32), 512, 0, stream>>>(ab, wpbt, b_proj, out);
}

// Round 20
// 101.385 us; speedup vs baseline: 1.1613x; 1.0051x over previous
//
#include <hip/hip_runtime.h>
#include <cstdint>
#include <cstddef>

typedef __bf16 bf16x8 __attribute__((ext_vector_type(8)));
typedef float f32x4 __attribute__((ext_vector_type(4)));

#define MFMA16(a, b, c) __builtin_amdgcn_mfma_f32_16x16x32_bf16(a, b, c, 0, 0, 0)

static __device__ __forceinline__ bf16x8 ld_bf16x8(const __bf16* p) {
    return *reinterpret_cast<const bf16x8*>(p);
}

static __device__ __forceinline__ void async_cp16(const __bf16* g, __bf16* l) {
    __builtin_amdgcn_global_load_lds((const __attribute__((address_space(1))) void*)g,
                                     (__attribute__((address_space(3))) void*)l, 16, 0, 0);
}

template <int N>
static __device__ __forceinline__ void wait_vmcnt() {
    asm volatile("s_waitcnt vmcnt(%0)" ::"n"(N) : "memory");
}

static __device__ __forceinline__ void barrier_pinned() {
    __builtin_amdgcn_sched_barrier(0);
    __builtin_amdgcn_s_barrier();
    __builtin_amdgcn_sched_barrier(0);
}

static __device__ __forceinline__ float ex2(float x) {
    return __builtin_amdgcn_exp2f(x);  // native v_exp_f32
}

// ---- DPP 16-lane rotate-reduce (pure VALU, no DS pipe) ----
template <int CTRL>
static __device__ __forceinline__ float dppmv(float x) {
    return __builtin_bit_cast(float, __builtin_amdgcn_update_dpp(
        0, __builtin_bit_cast(int, x), CTRL, 0xF, 0xF, true));
}
static __device__ __forceinline__ float rmax16(float x) {
    x = fmaxf(x, dppmv<0x121>(x));
    x = fmaxf(x, dppmv<0x122>(x));
    x = fmaxf(x, dppmv<0x124>(x));
    x = fmaxf(x, dppmv<0x128>(x));
    return x;
}
static __device__ __forceinline__ float rsum16(float x) {
    x += dppmv<0x121>(x);
    x += dppmv<0x122>(x);
    x += dppmv<0x124>(x);
    x += dppmv<0x128>(x);
    return x;
}

// ---------------- merged prep: f32->bf16 convert + 2 transpose-converts ----------------
static __device__ __forceinline__ void tcvt_body(const float* __restrict__ in,
                                                 __bf16* __restrict__ out, int K, int N,
                                                 int bx, int by, __bf16 (*T)[72]) {
    const int k0 = by * 64, n0 = bx * 64;
    const int t = threadIdx.x;
    const int col = (t & 15) << 2;
    const int rowb = t >> 4;
    #pragma unroll
    for (int i = 0; i < 4; i++) {
        int row = i * 16 + rowb;
        float4 v = *reinterpret_cast<const float4*>(&in[(size_t)(k0 + row) * N + n0 + col]);
        T[col + 0][row] = (__bf16)v.x;
        T[col + 1][row] = (__bf16)v.y;
        T[col + 2][row] = (__bf16)v.z;
        T[col + 3][row] = (__bf16)v.w;
    }
    __syncthreads();
    const int oc = (t & 7) << 3;
    const int orb = t >> 3;
    #pragma unroll
    for (int i = 0; i < 2; i++) {
        int r = i * 32 + orb;
        bf16x8 v = *reinterpret_cast<bf16x8*>(&T[r][oc]);
        *reinterpret_cast<bf16x8*>(&out[(size_t)(n0 + r) * K + k0 + oc]) = v;
    }
}

__global__ __launch_bounds__(256) void prep_kernel(const float* __restrict__ x,
                                                   __bf16* __restrict__ xb,
                                                   const float* __restrict__ wa,
                                                   __bf16* __restrict__ wabt,
                                                   const float* __restrict__ wp,
                                                   __bf16* __restrict__ wpbt) {
    __shared__ __bf16 T[64][72];
    const int bid = blockIdx.x;
    if (bid < 2048) {
        int i = bid * 256 + threadIdx.x;
        const float4* s4 = reinterpret_cast<const float4*>(x) + (size_t)i * 2;
        float4 a = s4[0], b = s4[1];
        bf16x8 o;
        o[0] = (__bf16)a.x; o[1] = (__bf16)a.y; o[2] = (__bf16)a.z; o[3] = (__bf16)a.w;
        o[4] = (__bf16)b.x; o[5] = (__bf16)b.y; o[6] = (__bf16)b.z; o[7] = (__bf16)b.w;
        reinterpret_cast<bf16x8*>(xb)[i] = o;
    } else if (bid < 2816) {
        const int t = bid - 2048;  // 768 tiles: 48 x 16
        tcvt_body(wa, wabt, 1024, 3072, t % 48, t / 48, T);
    } else {
        const int t = bid - 2816;  // 256 tiles: 16 x 16
        tcvt_body(wp, wpbt, 1024, 1024, t % 16, t / 16, T);
    }
}

// ---------------- 3-buffer depth-2 counted-vmcnt mainloop, chunk-XOR swizzled ----------
template <int BM, int BN, int WM, int WN>
__device__ __forceinline__ void mainloop2(const __bf16* __restrict__ A,
                                          const __bf16* __restrict__ Bt,
                                          int K, int row0, int col0,
                                          __bf16* lds,
                                          f32x4 (&acc)[BM / WM / 16][BN / WN / 16]) {
    constexpr int MR = BM / WM / 16, NR = BN / WN / 16;
    constexpr int AE = BM * 32;
    constexpr int BUFE = AE + BN * 32;
    constexpr int APW = BM / 16 / 8;
    constexpr int BPW = BN / 16 / 8;
    const int tid = threadIdx.x, l = tid & 63, w = tid >> 6;
    const int wm = w / WN, wn = w % WN;
    const int lr = l >> 2;
    const int lcs = (((l & 3) ^ ((l >> 3) & 3)) << 3);  // pre-swizzled source k-offset
    const int fr = l & 15;
    const int fc = (((l >> 4) ^ ((l >> 1) & 3)) << 3);  // swizzled read k-offset

    const size_t arow = (size_t)(row0 + lr) * K + lcs;
    const size_t brow = (size_t)(col0 + lr) * K + lcs;
    const int nt = K >> 5;

    auto stage = [&](int t, int buf) {
        const int k0 = t << 5;
        const int bb = buf * BUFE;
        #pragma unroll
        for (int j = 0; j < APW; j++) {
            const int mi = w * APW + j;
            async_cp16(A + arow + (size_t)mi * 16 * K + k0, lds + bb + mi * 512 + l * 8);
        }
        #pragma unroll
        for (int j = 0; j < BPW; j++) {
            const int ni = w * BPW + j;
            async_cp16(Bt + brow + (size_t)ni * 16 * K + k0, lds + bb + AE + ni * 512 + l * 8);
        }
    };

    stage(0, 0);
    stage(1, 1);

    const int aoff = (wm * (BM / WM) + fr) * 32 + fc;
    const int boff = AE + (wn * (BN / WN) + fr) * 32 + fc;

    int p = 0;
    for (int t = 0; t < nt; ++t) {
        if (t + 1 < nt) {
            wait_vmcnt<APW + BPW>();
        } else {
            wait_vmcnt<0>();
        }
        barrier_pinned();
        if (t + 2 < nt) {
            int p2 = p + 2; if (p2 >= 3) p2 -= 3;
            stage(t + 2, p2);
        }
        const int cb = p * BUFE;
        bf16x8 af[MR], bfv[NR];
        #pragma unroll
        for (int m = 0; m < MR; m++) af[m] = ld_bf16x8(&lds[cb + aoff + m * 512]);
        #pragma unroll
        for (int n = 0; n < NR; n++) bfv[n] = ld_bf16x8(&lds[cb + boff + n * 512]);
        __builtin_amdgcn_s_setprio(1);
        #pragma unroll
        for (int m = 0; m < MR; m++) {
            #pragma unroll
            for (int n = 0; n < NR; n++) {
                acc[m][n] = MFMA16(af[m], bfv[n], acc[m][n]);
            }
        }
        __builtin_amdgcn_s_setprio(0);
        asm volatile("s_waitcnt lgkmcnt(0)" ::: "memory");
        __builtin_amdgcn_sched_barrier(0);
        p = (p == 2) ? 0 : p + 1;
    }
}

// ---------------- QKV GEMM: x(4096x1024) @ w_attn^T(3072x1024) + b_attn ----------------
__global__ __launch_bounds__(512, 2) void gemm_qkv_kernel(const __bf16* __restrict__ xb,
                                                          const __bf16* __restrict__ wabt,
                                                          const float* __restrict__ bias,
                                                          __bf16* __restrict__ qb,
                                                          __bf16* __restrict__ kb,
                                                          __bf16* __restrict__ vt,
                                                          float* __restrict__ present) {
    __shared__ __bf16 lds[3 * (128 * 32 + 128 * 32)];  // 48 KB
    f32x4 acc[2][4] = {};
    const int row0 = blockIdx.y * 128, col0 = blockIdx.x * 128;
    mainloop2<128, 128, 4, 2>(xb, wabt, 1024, row0, col0, lds, acc);

    const int l = threadIdx.x & 63, w = threadIdx.x >> 6;
    const int wm = w >> 1, wn = w & 1;
    const int part = col0 >> 10;  // uniform per block: 0=q 1=k 2=v
    #pragma unroll
    for (int n = 0; n < 4; n++) {
        int col = col0 + wn * 64 + n * 16 + (l & 15);
        int hh = (col >> 6) & 15;
        int dd = col & 63;
        float bv = bias[col];
        #pragma unroll
        for (int m = 0; m < 2; m++) {
            #pragma unroll
            for (int r = 0; r < 4; r++) {
                int row = row0 + wm * 32 + m * 16 + ((l >> 4) << 2) + r;
                int bb = row >> 11, ss = row & 2047;
                float val = acc[m][n][r] + bv;
                size_t qi = (((size_t)(bb * 16 + hh)) * 2048 + ss) * 64 + dd;
                if (part == 0) {
                    qb[qi] = (__bf16)val;
                } else if (part == 1) {
                    kb[qi] = (__bf16)val;
                    present[(((size_t)((bb * 2 + 0) * 16 + hh)) * 2048 + ss) * 64 + dd] = val;
                } else {
                    vt[(((size_t)(bb * 16 + hh)) * 64 + dd) * 2048 + ss] = (__bf16)val;
                    present[(((size_t)((bb * 2 + 1) * 16 + hh)) * 2048 + ss) * 64 + dd] = val;
                }
            }
        }
    }
}

// ---------------- proj mainloop: 128x64 tile, 8 waves (4Mx2N), uneven staging ----------
// A = 8 chunks (one per wave); B = 4 chunks (waves 0-3). Per-wave counted vmcnt:
// w<4 stages 2 loads/K-step -> wait(2); w>=4 stages 1 -> wait(1); barrier globalizes
// the per-wave certificates (each chunk certified by its stager before any reader
// proceeds). Same chunk-XOR swizzle; key (row>>1)&3 with 16-aligned bases.
__device__ __forceinline__ void mainloop_pj(const __bf16* __restrict__ A,
                                            const __bf16* __restrict__ Bt,
                                            int K, int row0, int col0,
                                            __bf16* lds, f32x4 (&acc)[2][2]) {
    constexpr int AE = 128 * 32;        // 4096 elems
    constexpr int BUFE = AE + 64 * 32;  // 6144 elems (12 KB)
    const int tid = threadIdx.x, l = tid & 63, w = tid >> 6;
    const int wm = w >> 1, wn = w & 1;  // 4M x 2N
    const int lr = l >> 2;
    const int lcs = (((l & 3) ^ ((l >> 3) & 3)) << 3);
    const int fr = l & 15;
    const int fc = (((l >> 4) ^ ((l >> 1) & 3)) << 3);
    const bool hasB = (w < 4);

    const size_t arow = (size_t)(row0 + w * 16 + lr) * K + lcs;
    const size_t brow = (size_t)(col0 + (w & 3) * 16 + lr) * K + lcs;
    const int nt = K >> 5;

    auto stage = [&](int t, int buf) {
        const int k0 = t << 5;
        const int bb = buf * BUFE;
        async_cp16(A + arow + k0, lds + bb + w * 512 + l * 8);
        if (hasB) async_cp16(Bt + brow + k0, lds + bb + AE + w * 512 + l * 8);
    };

    stage(0, 0);
    stage(1, 1);

    const int aoff = (wm * 32 + fr) * 32 + fc;
    const int boff = AE + (wn * 32 + fr) * 32 + fc;

    int p = 0;
    for (int t = 0; t < nt; ++t) {
        if (t + 1 < nt) {
            if (hasB) wait_vmcnt<2>();
            else wait_vmcnt<1>();
        } else {
            wait_vmcnt<0>();
        }
        barrier_pinned();
        if (t + 2 < nt) {
            int p2 = p + 2; if (p2 >= 3) p2 -= 3;
            stage(t + 2, p2);
        }
        const int cb = p * BUFE;
        bf16x8 af[2], bfv[2];
        #pragma unroll
        for (int m = 0; m < 2; m++) af[m] = ld_bf16x8(&lds[cb + aoff + m * 512]);
        #pragma unroll
        for (int n = 0; n < 2; n++) bfv[n] = ld_bf16x8(&lds[cb + boff + n * 512]);
        __builtin_amdgcn_s_setprio(1);
        #pragma unroll
        for (int m = 0; m < 2; m++) {
            #pragma unroll
            for (int n = 0; n < 2; n++) {
                acc[m][n] = MFMA16(af[m], bfv[n], acc[m][n]);
            }
        }
        __builtin_amdgcn_s_setprio(0);
        asm volatile("s_waitcnt lgkmcnt(0)" ::: "memory");
        __builtin_amdgcn_sched_barrier(0);
        p = (p == 2) ? 0 : p + 1;
    }
}

// ---------------- Proj GEMM: a(4096x1024) @ w_proj^T(1024x1024) + b_proj ----------------
// 128x64 tile, grid 16x32 = 512 blocks = 2/CU (was 256 = 1/CU: no cross-block TLP).
__global__ __launch_bounds__(512, 2) void gemm_proj_kernel(const __bf16* __restrict__ ab,
                                                           const __bf16* __restrict__ wpbt,
                                                           const float* __restrict__ bias,
                                                           float* __restrict__ out) {
    __shared__ __bf16 lds[3 * (128 * 32 + 64 * 32)];  // 36 KB
    f32x4 acc[2][2] = {};
    const int row0 = blockIdx.y * 128, col0 = blockIdx.x * 64;
    mainloop_pj(ab, wpbt, 1024, row0, col0, lds, acc);

    const int l = threadIdx.x & 63, w = threadIdx.x >> 6;
    const int wm = w >> 1, wn = w & 1;
    #pragma unroll
    for (int n = 0; n < 2; n++) {
        int col = col0 + wn * 32 + n * 16 + (l & 15);
        float bv = bias[col];
        #pragma unroll
        for (int m = 0; m < 2; m++) {
            #pragma unroll
            for (int r = 0; r < 4; r++) {
                int row = row0 + wm * 32 + m * 16 + ((l >> 4) << 2) + r;
                out[(size_t)row * 1024 + col] = acc[m][n][r] + bv;
            }
        }
    }
}

// ---------------- sliding-window causal flash attention, LDS-staged two-pass ----
__global__ __launch_bounds__(256, 3) void attn_kernel(const __bf16* __restrict__ qb,
                                                      const __bf16* __restrict__ kb,
                                                      const __bf16* __restrict__ vtb,
                                                      __bf16* __restrict__ ab) {
    __shared__ __bf16 Kls[5 * 4096];     // 40 KB: [tile][row 64][elem 64] swizzled
    __shared__ __bf16 Pls[4][16 * 72];   // 9.2 KB per-wave P tiles
    const int bidx = blockIdx.x;
    const int xcd = bidx & 7, idx = bidx >> 3;
    const int bh = (xcd << 2) | (idx & 3);  // 4 heads per XCD (K/V L2-resident)
    const int qc = idx >> 2;                // 64-row q-chunk, 0..31
    const int lane = threadIdx.x & 63, wid = threadIdx.x >> 6;
    const int q0blk = qc * 64;
    const int q0w = q0blk + wid * 16;

    const __bf16* Qh = qb + (size_t)bh * 2048 * 64;
    const __bf16* Kh = kb + (size_t)bh * 2048 * 64;
    const __bf16* Vt = vtb + (size_t)bh * 64 * 2048;
    __bf16* Pw = &Pls[wid][0];

    const int ld16 = lane & 15, hi3 = (lane >> 4) << 3, hi4 = (lane >> 4) << 2;

    int tmp = q0blk - 255;
    const int kt0 = tmp > 0 ? (tmp & ~63) : 0;
    const int NT = ((q0blk + 63 - kt0) >> 6) + 1;  // <= 5

    // ---- stage all K tiles (block-cooperative, source-preswizzled) ----
    const int sswz = (((lane & 7) ^ (lane >> 3)) << 3);  // src elem offset (swizzled)
    for (int j = wid; j < NT * 8; j += 4) {
        const int tj = j >> 3, c = j & 7;
        const int kt = kt0 + tj * 64;
        const __bf16* src = Kh + (size_t)(kt + c * 8 + (lane >> 3)) * 64 + sswz;
        async_cp16(src, &Kls[j * 512 + lane * 8]);
    }

    bf16x8 qf[2];
    {
        const __bf16* qp = Qh + (size_t)(q0w + ld16) * 64 + hi3;
        qf[0] = ld_bf16x8(qp);
        qf[1] = ld_bf16x8(qp + 32);
    }
    wait_vmcnt<0>();
    __syncthreads();  // all waves' staging landed

    const float cl2 = 0.18033688f;  // (1/sqrt(64)) * log2(e)
    const int rdswz = (lane & 7) << 3;  // read-side XOR key

    auto qks = [&](int t, int kt, f32x4 (&s)[4]) {
        const __bf16* tb = &Kls[t * 4096];
        #pragma unroll
        for (int kc = 0; kc < 4; kc++) {
            const int rbase = (kc * 16 + ld16) * 64;
            bf16x8 k0 = ld_bf16x8(&tb[rbase + ((hi3) ^ rdswz)]);
            bf16x8 k1 = ld_bf16x8(&tb[rbase + ((32 + hi3) ^ rdswz)]);
            f32x4 a = (f32x4){0.f, 0.f, 0.f, 0.f};
            a = MFMA16(qf[0], k0, a);
            a = MFMA16(qf[1], k1, a);
            s[kc] = a;
        }
        const bool clean = (kt >= q0w - 240) && (kt + 63 <= q0w);  // wave-uniform
        if (!clean) {
            #pragma unroll
            for (int r = 0; r < 4; r++) {
                int q = q0w + hi4 + r;
                #pragma unroll
                for (int kc = 0; kc < 4; kc++) {
                    int ki = kt + kc * 16 + ld16;
                    bool ok = (ki <= q) && (ki > q - 256);
                    s[kc][r] = ok ? s[kc][r] : -1e30f;
                }
            }
        }
    };

    // ---- pass 1: exact row max over the wave's window ----
    float mr[4] = {-1e30f, -1e30f, -1e30f, -1e30f};
    for (int t = 0; t < NT; t++) {
        const int kt = kt0 + t * 64;
        if (kt + 63 < q0w - 255 || kt > q0w + 15) continue;
        f32x4 s[4];
        qks(t, kt, s);
        #pragma unroll
        for (int r = 0; r < 4; r++) {
            mr[r] = fmaxf(mr[r], fmaxf(fmaxf(s[0][r], s[1][r]), fmaxf(s[2][r], s[3][r])));
        }
    }
    float m2[4];
    #pragma unroll
    for (int r = 0; r < 4; r++) m2[r] = rmax16(mr[r]) * cl2;

    // ---- pass 2: exp, P roundtrip, PV ----
    f32x4 o[4];
    #pragma unroll
    for (int dt = 0; dt < 4; dt++) o[dt] = (f32x4){0.f, 0.f, 0.f, 0.f};
    float sl[4] = {0.f, 0.f, 0.f, 0.f};

    for (int t = 0; t < NT; t++) {
        const int kt = kt0 + t * 64;
        if (kt + 63 < q0w - 255 || kt > q0w + 15) continue;
        bf16x8 va[4], vb[4];
        #pragma unroll
        for (int dt = 0; dt < 4; dt++) {
            const __bf16* vp = &Vt[(size_t)(dt * 16 + ld16) * 2048 + kt + hi3];
            va[dt] = ld_bf16x8(vp);
            vb[dt] = ld_bf16x8(vp + 32);
        }
        f32x4 s[4];
        qks(t, kt, s);
        #pragma unroll
        for (int r = 0; r < 4; r++) {
            float p0 = ex2(fmaf(s[0][r], cl2, -m2[r]));
            float p1 = ex2(fmaf(s[1][r], cl2, -m2[r]));
            float p2 = ex2(fmaf(s[2][r], cl2, -m2[r]));
            float p3 = ex2(fmaf(s[3][r], cl2, -m2[r]));
            sl[r] += (p0 + p1) + (p2 + p3);
            int qrow = hi4 + r;
            Pw[qrow * 72 + ld16]      = (__bf16)p0;
            Pw[qrow * 72 + 16 + ld16] = (__bf16)p1;
            Pw[qrow * 72 + 32 + ld16] = (__bf16)p2;
            Pw[qrow * 72 + 48 + ld16] = (__bf16)p3;
        }
        asm volatile("s_waitcnt lgkmcnt(0)" ::: "memory");
        bf16x8 pfA = ld_bf16x8(&Pw[ld16 * 72 + hi3]);
        bf16x8 pfB = ld_bf16x8(&Pw[ld16 * 72 + 32 + hi3]);
        __builtin_amdgcn_s_setprio(1);
        #pragma unroll
        for (int dt = 0; dt < 4; dt++) o[dt] = MFMA16(pfA, va[dt], o[dt]);
        #pragma unroll
        for (int dt = 0; dt < 4; dt++) o[dt] = MFMA16(pfB, vb[dt], o[dt]);
        __builtin_amdgcn_s_setprio(0);
    }

    // ---- normalize and store ----
    const int bb = bh >> 4, hh = bh & 15;
    #pragma unroll
    for (int r = 0; r < 4; r++) {
        float inv = 1.f / rsum16(sl[r]);
        int q = q0w + hi4 + r;
        size_t base = ((size_t)bb * 2048 + q) * 1024 + hh * 64;
        #pragma unroll
        for (int dt = 0; dt < 4; dt++) {
            ab[base + dt * 16 + ld16] = (__bf16)(o[dt][r] * inv);
        }
    }
}

// ---------------- launch ----------------
extern "C" void kernel_launch(void* const* d_in, const int* in_sizes, int n_in,
                              void* d_out, int out_size, void* d_ws, size_t ws_size,
                              hipStream_t stream) {
    const float* x = (const float*)d_in[0];
    const float* w_attn = (const float*)d_in[1];
    const float* b_attn = (const float*)d_in[2];
    const float* w_proj = (const float*)d_in[3];
    const float* b_proj = (const float*)d_in[4];

    float* out = (float*)d_out;
    float* present = out + (size_t)2 * 2048 * 1024;

    char* w = (char*)d_ws;
    __bf16* xb   = (__bf16*)(w);
    __bf16* wabt = (__bf16*)(w + 8388608);
    __bf16* wpbt = (__bf16*)(w + 14680064);
    __bf16* qb   = (__bf16*)(w + 16777216);
    __bf16* kb   = (__bf16*)(w + 25165824);
    __bf16* vt   = (__bf16*)(w + 33554432);
    __bf16* ab   = xb;

    prep_kernel<<<3072, 256, 0, stream>>>(x, xb, w_attn, wabt, w_proj, wpbt);

    gemm_qkv_kernel<<<dim3(24, 32), 512, 0, stream>>>(xb, wabt, b_attn, qb, kb, vt, present);

    attn_kernel<<<1024, 256, 0, stream>>>(qb, kb, vt, ab);

    gemm_proj_kernel<<<dim3(16, 32), 512, 0, stream>>>(ab, wpbt, b_proj, out);
}